// Round 3
// baseline (1680.239 us; speedup 1.0000x reference)
//
#include <hip/hip_runtime.h>
#include <hip/hip_bf16.h>

// B=16384 rows of logits[B,4096]; prototypes[4096,768]; boundaries[4096]
#define NB 16384
#define NC 4096
#define ND 768
#define NT 32              // 4096/128 tiles per dim
#define NIC 528            // NT*(NT+1)/2 upper-triangle tile pairs
#define NGRID (NB + NIC)   // 16912

#define WS_NLL 0           // float nll[16384]
#define WS_ICP 65536       // float icp[528]

typedef __bf16 bf16x8 __attribute__((ext_vector_type(8)));
typedef float  f32x4  __attribute__((ext_vector_type(4)));

__device__ __forceinline__ unsigned short f2bf(float f) {
    return __builtin_bit_cast(unsigned short, __float2bfloat16(f));
}

// One kernel, two block roles:
//  - blockIdx % 32 == 31  -> IC tile block (528 of them, upper-tri incl diag)
//  - otherwise            -> CE row block (16384 of them, 1 row each)
// CE is HBM-bound, IC is MFMA/VALU-bound; interleaving roles in dispatch order
// lets the two overlap on the machine instead of serializing on the stream.
// NOTE: no min-waves clause in __launch_bounds__ — R2 showed that forcing
// 3 waves/EU caps VGPRs at 84 and spills the 64-VGPR accumulator to scratch
// (WRITE_SIZE 500 MB, 11x regression). Let the allocator have its ~170.
__global__ __launch_bounds__(256) void fused_kernel(
    const float* __restrict__ logits, const int* __restrict__ targets,
    const float* __restrict__ prot, const float* __restrict__ bnd,
    float* __restrict__ nll, float* __restrict__ icp)
{
    __shared__ __bf16 As[128][72];   // +8 pad: 2-way bank alias only (free)
    __shared__ __bf16 Bs[128][72];
    __shared__ float t1A[128], t1B[128];
    __shared__ float redf[4];
    __shared__ float smx[4], ssm[4];

    const int b = blockIdx.x;
    const int tid = threadIdx.x;

    if ((b & 31) != 31) {
        // ---------------- CE: one logits row, full logsumexp in registers ----
        const int row = b - ((b + 1) >> 5);
        const float4* rp = reinterpret_cast<const float4*>(logits + (size_t)row * NC);
        float4 v[4];
#pragma unroll
        for (int i = 0; i < 4; ++i) v[i] = rp[tid + 256 * i];     // 1024 float4/row
        float m = -3.4e38f;
#pragma unroll
        for (int i = 0; i < 4; ++i)
            m = fmaxf(m, fmaxf(fmaxf(v[i].x, v[i].y), fmaxf(v[i].z, v[i].w)));
        float s = 0.f;
#pragma unroll
        for (int i = 0; i < 4; ++i)
            s += __expf(v[i].x - m) + __expf(v[i].y - m) + __expf(v[i].z - m) + __expf(v[i].w - m);
#pragma unroll
        for (int off = 32; off; off >>= 1) {
            float mo = __shfl_xor(m, off);
            float so = __shfl_xor(s, off);
            float mn = fmaxf(m, mo);
            s = s * __expf(m - mn) + so * __expf(mo - mn);
            m = mn;
        }
        int w = tid >> 6, lane = tid & 63;
        if (lane == 0) { smx[w] = m; ssm[w] = s; }
        __syncthreads();
        if (tid == 0) {
            float M = smx[0], S = ssm[0];
#pragma unroll
            for (int i = 1; i < 4; ++i) {
                float mn = fmaxf(M, smx[i]);
                S = S * __expf(M - mn) + ssm[i] * __expf(smx[i] - mn);
                M = mn;
            }
            int t = targets[row];
            float xt = logits[(size_t)row * NC + t];
            nll[row] = M + __logf(S) - xt;
        }
        return;
    }

    // ---------------- IC: 128x128 Gram tile for tile-pair (bi<=bj) ----------
    const int icid = b >> 5;
    int u = icid, bi = 0;
    while (u >= NT - bi) { u -= NT - bi; ++bi; }
    const int bj = bi + u;
    const bool diag = (bi == bj);
    const int row0 = bi * 128, col0 = bj * 128;

    const int lane = tid & 63, w = tid >> 6;
    const int fr = lane & 15, fq = lane >> 4;
    const int wrow = (w >> 1) * 64, wcol = (w & 1) * 64;

    f32x4 acc[4][4];
#pragma unroll
    for (int mi = 0; mi < 4; ++mi)
#pragma unroll
        for (int nj = 0; nj < 4; ++nj) acc[mi][nj] = (f32x4){0.f, 0.f, 0.f, 0.f};

    float ssA[8], ssB[8];
#pragma unroll
    for (int i = 0; i < 8; ++i) { ssA[i] = 0.f; ssB[i] = 0.f; }

    const float* Ap = prot + (size_t)row0 * ND;
    const float* Bp = prot + (size_t)col0 * ND;

    for (int kt = 0; kt < ND / 64; ++kt) {
#pragma unroll
        for (int s2 = 0; s2 < 8; ++s2) {
            int c = tid + 256 * s2;              // 2048 float4-chunks per tile
            int r = c >> 4, k4 = c & 15;
            float4 va = *reinterpret_cast<const float4*>(Ap + (size_t)r * ND + kt * 64 + k4 * 4);
            ssA[s2] += va.x * va.x + va.y * va.y + va.z * va.z + va.w * va.w;
            ushort4 ha; ha.x = f2bf(va.x); ha.y = f2bf(va.y); ha.z = f2bf(va.z); ha.w = f2bf(va.w);
            *reinterpret_cast<ushort4*>(&As[r][k4 * 4]) = ha;
            float4 vb = *reinterpret_cast<const float4*>(Bp + (size_t)r * ND + kt * 64 + k4 * 4);
            ssB[s2] += vb.x * vb.x + vb.y * vb.y + vb.z * vb.z + vb.w * vb.w;
            ushort4 hb; hb.x = f2bf(vb.x); hb.y = f2bf(vb.y); hb.z = f2bf(vb.z); hb.w = f2bf(vb.w);
            *reinterpret_cast<ushort4*>(&Bs[r][k4 * 4]) = hb;
        }
        __syncthreads();
#pragma unroll
        for (int ks = 0; ks < 64; ks += 32) {
            bf16x8 af[4], bfv[4];
#pragma unroll
            for (int mi = 0; mi < 4; ++mi)
                af[mi] = *reinterpret_cast<const bf16x8*>(&As[wrow + mi * 16 + fr][ks + fq * 8]);
#pragma unroll
            for (int nj = 0; nj < 4; ++nj)
                bfv[nj] = *reinterpret_cast<const bf16x8*>(&Bs[wcol + nj * 16 + fr][ks + fq * 8]);
#pragma unroll
            for (int mi = 0; mi < 4; ++mi)
#pragma unroll
                for (int nj = 0; nj < 4; ++nj)
                    acc[mi][nj] = __builtin_amdgcn_mfma_f32_16x16x32_bf16(af[mi], bfv[nj], acc[mi][nj], 0, 0, 0);
        }
        __syncthreads();
    }

    // per-row ||p||^2 (fp32 exact, accumulated during staging) -> t1 in LDS
#pragma unroll
    for (int s2 = 0; s2 < 8; ++s2) {
        float a = ssA[s2], c2 = ssB[s2];
#pragma unroll
        for (int off = 1; off < 16; off <<= 1) {
            a  += __shfl_xor(a, off);
            c2 += __shfl_xor(c2, off);
        }
        if ((tid & 15) == 0) {
            int r = s2 * 16 + (tid >> 4);
            t1A[r] = (1.f - bnd[row0 + r]) * a;
            t1B[r] = (1.f - bnd[col0 + r]) * c2;
        }
    }
    __syncthreads();

    // epilogue: off-diag tile-pairs contribute BOTH (i,j) and (j,i) orders
    float t1a[16], ba1[16];
#pragma unroll
    for (int mi = 0; mi < 4; ++mi)
#pragma unroll
        for (int e = 0; e < 4; ++e) {
            int il = wrow + mi * 16 + fq * 4 + e;
            t1a[mi * 4 + e] = t1A[il];
            ba1[mi * 4 + e] = bnd[row0 + il] - 1.f;
        }
    float t1b[4], bb1[4];
#pragma unroll
    for (int nj = 0; nj < 4; ++nj) {
        int jl = wcol + nj * 16 + fr;
        t1b[nj] = t1B[jl];
        bb1[nj] = bnd[col0 + jl] - 1.f;
    }

    float sum = 0.f;
#pragma unroll
    for (int mi = 0; mi < 4; ++mi) {
#pragma unroll
        for (int nj = 0; nj < 4; ++nj) {
#pragma unroll
            for (int e = 0; e < 4; ++e) {
                float G = acc[mi][nj][e];
                float tij = t1a[mi * 4 + e] + bb1[nj] * G;   // (i in A, j in B)
                if (diag) {
                    int il = wrow + mi * 16 + fq * 4 + e;
                    int jl = wcol + nj * 16 + fr;
                    if (il != jl) sum += fmaxf(tij, 0.f);
                } else {
                    float tji = t1b[nj] + ba1[mi * 4 + e] * G; // (j in B, i in A) mirrored
                    sum += fmaxf(tij, 0.f) + fmaxf(tji, 0.f);
                }
            }
        }
    }
#pragma unroll
    for (int off = 32; off; off >>= 1) sum += __shfl_xor(sum, off);
    if (lane == 0) redf[w] = sum;
    __syncthreads();
    if (tid == 0) icp[icid] = redf[0] + redf[1] + redf[2] + redf[3];
}

// ---------------- finalize: deterministic ordered reduction ----------------
__global__ __launch_bounds__(1024) void fin_kernel(const float* __restrict__ nll,
                                                   const float* __restrict__ icp,
                                                   float* __restrict__ out) {
    int tid = threadIdx.x;
    double s = 0.0;
    for (int i = tid; i < NB; i += 1024) s += (double)nll[i];
    double s2 = (tid < NIC) ? (double)icp[tid] : 0.0;
#pragma unroll
    for (int off = 32; off; off >>= 1) {
        s  += __shfl_xor(s, off);
        s2 += __shfl_xor(s2, off);
    }
    __shared__ double sm[16], sm2[16];
    int w = tid >> 6, lane = tid & 63;
    if (lane == 0) { sm[w] = s; sm2[w] = s2; }
    __syncthreads();
    if (tid == 0) {
        double a = 0.0, c = 0.0;
        for (int i = 0; i < 16; ++i) { a += sm[i]; c += sm2[i]; }
        double cls = a / (double)NB;
        double ic  = c / ((double)NC * (double)(NC - 1));
        out[0] = (float)(cls + 0.05 * ic);
        out[1] = (float)cls;
        out[2] = (float)ic;
    }
}

extern "C" void kernel_launch(void* const* d_in, const int* in_sizes, int n_in,
                              void* d_out, int out_size, void* d_ws, size_t ws_size,
                              hipStream_t stream) {
    const float* logits  = (const float*)d_in[0];
    const int*   targets = (const int*)d_in[1];
    const float* prot    = (const float*)d_in[2];
    const float* bnd     = (const float*)d_in[3];
    float* out = (float*)d_out;
    char* ws = (char*)d_ws;
    float* nll = (float*)(ws + WS_NLL);
    float* icp = (float*)(ws + WS_ICP);

    fused_kernel<<<NGRID, 256, 0, stream>>>(logits, targets, prot, bnd, nll, icp);
    fin_kernel<<<1, 1024, 0, stream>>>(nll, icp, out);
}

// Round 4
// 91.279 us; speedup vs baseline: 18.4077x; 18.4077x over previous
//
#include <hip/hip_runtime.h>
#include <hip/hip_bf16.h>

// B=16384 rows of logits[B,4096]; prototypes[4096,768]; boundaries[4096]
#define NB 16384
#define NC 4096
#define ND 768
#define NT 32              // 4096/128 tiles per dim
#define NIC 528            // NT*(NT+1)/2 upper-triangle tile pairs (symmetry)

// ws layout:
#define WS_NLL 0           // float nll[16384]
#define WS_ICP 65536       // float icp[528]
#define WS_T1  69632       // float t1[4096] = (1-b_i)*||p_i||^2 (fp32 exact)
#define WS_P16 86016       // ushort P16[4096*768] bf16 prototypes

// LESSON (R2/R3): fusing CE+IC into one kernel merges register pressure;
// the IC path (64-VGPR acc + pipelined staging + epilogue) spills to scratch
// and every block pays the fat occupancy footprint -> 11-19x regression.
// Separate kernels keep CE lean (high waves/CU) and IC spill-free.

typedef __bf16 bf16x8 __attribute__((ext_vector_type(8)));
typedef float  f32x4  __attribute__((ext_vector_type(4)));

__device__ __forceinline__ unsigned short f2bf(float f) {
    return __builtin_bit_cast(unsigned short, __float2bfloat16(f));
}

// ---------------- prep: per-row ||p||^2 (fp32) + bf16 convert ----------------
template<bool PRECONV>
__global__ __launch_bounds__(256) void prep_kernel(const float* __restrict__ prot,
                                                   const float* __restrict__ bnd,
                                                   float* __restrict__ t1,
                                                   unsigned short* __restrict__ P16) {
    int w = threadIdx.x >> 6;
    int lane = threadIdx.x & 63;
    int row = blockIdx.x * 4 + w;
    const float4* rp = reinterpret_cast<const float4*>(prot + (size_t)row * ND);
    float ss = 0.f;
#pragma unroll
    for (int it = 0; it < 3; ++it) {
        int idx = it * 64 + lane;            // 192 float4 per row
        float4 v = rp[idx];
        ss += v.x * v.x + v.y * v.y + v.z * v.z + v.w * v.w;
        if (PRECONV) {
            ushort4 h;
            h.x = f2bf(v.x); h.y = f2bf(v.y); h.z = f2bf(v.z); h.w = f2bf(v.w);
            *reinterpret_cast<ushort4*>(P16 + (size_t)row * ND + idx * 4) = h;
        }
    }
#pragma unroll
    for (int off = 32; off; off >>= 1) ss += __shfl_xor(ss, off);
    if (lane == 0) t1[row] = (1.f - bnd[row]) * ss;
}

// ---------------- cross-entropy: one block per row ----------------
__global__ __launch_bounds__(256) void ce_kernel(const float* __restrict__ logits,
                                                 const int* __restrict__ targets,
                                                 float* __restrict__ nll) {
    int row = blockIdx.x;
    int tid = threadIdx.x;
    const float4* rp = reinterpret_cast<const float4*>(logits + (size_t)row * NC);
    float4 v[4];
#pragma unroll
    for (int i = 0; i < 4; ++i) v[i] = rp[tid + 256 * i];   // 1024 float4 per row
    float m = -3.4e38f;
#pragma unroll
    for (int i = 0; i < 4; ++i)
        m = fmaxf(m, fmaxf(fmaxf(v[i].x, v[i].y), fmaxf(v[i].z, v[i].w)));
    float s = 0.f;
#pragma unroll
    for (int i = 0; i < 4; ++i)
        s += __expf(v[i].x - m) + __expf(v[i].y - m) + __expf(v[i].z - m) + __expf(v[i].w - m);
#pragma unroll
    for (int off = 32; off; off >>= 1) {
        float mo = __shfl_xor(m, off);
        float so = __shfl_xor(s, off);
        float mn = fmaxf(m, mo);
        s = s * __expf(m - mn) + so * __expf(mo - mn);
        m = mn;
    }
    __shared__ float smx[4], ssm[4];
    int w = tid >> 6, lane = tid & 63;
    if (lane == 0) { smx[w] = m; ssm[w] = s; }
    __syncthreads();
    if (tid == 0) {
        float M = smx[0], S = ssm[0];
#pragma unroll
        for (int i = 1; i < 4; ++i) {
            float mn = fmaxf(M, smx[i]);
            S = S * __expf(M - mn) + ssm[i] * __expf(smx[i] - mn);
            M = mn;
        }
        int t = targets[row];
        float xt = logits[(size_t)row * NC + t];
        nll[row] = M + __logf(S) - xt;
    }
}

// ---------------- IC: symmetric 128x128 Gram tiles (upper-tri pairs) --------
// 528 blocks. Off-diag tile (bi<bj) computed ONCE, contributes both (i,j)
// and (j,i) constraint orders -> 0.52x the Gram FLOPs of the full matrix.
// Symmetry epilogue correctness was verified in R2/R3 (absmax 0.0).
template<bool PRECONV>
__global__ __launch_bounds__(256) void ic_kernel(const unsigned short* __restrict__ P16,
                                                 const float* __restrict__ prot,
                                                 const float* __restrict__ bnd,
                                                 const float* __restrict__ t1,
                                                 float* __restrict__ icp) {
    __shared__ __bf16 As[128][72];   // +8 pad (16B): 8-bank rotation per row
    __shared__ __bf16 Bs[128][72];
    const int tid = threadIdx.x;

    const int icid = blockIdx.x;
    int u = icid, bi = 0;
    while (u >= NT - bi) { u -= NT - bi; ++bi; }
    const int bj = bi + u;
    const bool diag = (bi == bj);
    const int row0 = bi * 128, col0 = bj * 128;

    const int lane = tid & 63, w = tid >> 6;
    const int fr = lane & 15, fq = lane >> 4;
    const int wrow = (w >> 1) * 64, wcol = (w & 1) * 64;

    f32x4 acc[4][4];
#pragma unroll
    for (int mi = 0; mi < 4; ++mi)
#pragma unroll
        for (int nj = 0; nj < 4; ++nj) acc[mi][nj] = (f32x4){0.f, 0.f, 0.f, 0.f};

    for (int kt = 0; kt < ND / 64; ++kt) {
        if (PRECONV) {
#pragma unroll
            for (int s2 = 0; s2 < 4; ++s2) {
                int c = tid + 256 * s2;          // 1024 chunks of 8 bf16 per tile
                int r = c >> 3, k8 = c & 7;
                uint4 va = *reinterpret_cast<const uint4*>(P16 + (size_t)(row0 + r) * ND + kt * 64 + k8 * 8);
                *reinterpret_cast<uint4*>(&As[r][k8 * 8]) = va;
                uint4 vb = *reinterpret_cast<const uint4*>(P16 + (size_t)(col0 + r) * ND + kt * 64 + k8 * 8);
                *reinterpret_cast<uint4*>(&Bs[r][k8 * 8]) = vb;
            }
        } else {
#pragma unroll
            for (int s2 = 0; s2 < 8; ++s2) {
                int c = tid + 256 * s2;          // 2048 chunks of 4 floats per tile
                int r = c >> 4, k4 = c & 15;
                float4 va = *reinterpret_cast<const float4*>(prot + (size_t)(row0 + r) * ND + kt * 64 + k4 * 4);
                ushort4 ha; ha.x = f2bf(va.x); ha.y = f2bf(va.y); ha.z = f2bf(va.z); ha.w = f2bf(va.w);
                *reinterpret_cast<ushort4*>(&As[r][k4 * 4]) = ha;
                float4 vb = *reinterpret_cast<const float4*>(prot + (size_t)(col0 + r) * ND + kt * 64 + k4 * 4);
                ushort4 hb; hb.x = f2bf(vb.x); hb.y = f2bf(vb.y); hb.z = f2bf(vb.z); hb.w = f2bf(vb.w);
                *reinterpret_cast<ushort4*>(&Bs[r][k4 * 4]) = hb;
            }
        }
        __syncthreads();
#pragma unroll
        for (int ks = 0; ks < 64; ks += 32) {
            bf16x8 af[4], bfv[4];
#pragma unroll
            for (int mi = 0; mi < 4; ++mi)
                af[mi] = *reinterpret_cast<const bf16x8*>(&As[wrow + mi * 16 + fr][ks + fq * 8]);
#pragma unroll
            for (int nj = 0; nj < 4; ++nj)
                bfv[nj] = *reinterpret_cast<const bf16x8*>(&Bs[wcol + nj * 16 + fr][ks + fq * 8]);
#pragma unroll
            for (int mi = 0; mi < 4; ++mi)
#pragma unroll
                for (int nj = 0; nj < 4; ++nj)
                    acc[mi][nj] = __builtin_amdgcn_mfma_f32_16x16x32_bf16(af[mi], bfv[nj], acc[mi][nj], 0, 0, 0);
        }
        __syncthreads();
    }

    // epilogue: tij = t1[i] + (b_j-1)*G ; off-diag pairs also add the mirror
    float t1a[16], ba1[16];
#pragma unroll
    for (int mi = 0; mi < 4; ++mi)
#pragma unroll
        for (int e = 0; e < 4; ++e) {
            int i = row0 + wrow + mi * 16 + fq * 4 + e;
            t1a[mi * 4 + e] = t1[i];
            ba1[mi * 4 + e] = bnd[i] - 1.f;
        }
    float t1b[4], bb1[4];
#pragma unroll
    for (int nj = 0; nj < 4; ++nj) {
        int j = col0 + wcol + nj * 16 + fr;
        t1b[nj] = t1[j];
        bb1[nj] = bnd[j] - 1.f;
    }

    float sum = 0.f;
#pragma unroll
    for (int mi = 0; mi < 4; ++mi) {
#pragma unroll
        for (int nj = 0; nj < 4; ++nj) {
#pragma unroll
            for (int e = 0; e < 4; ++e) {
                float G = acc[mi][nj][e];
                float tij = t1a[mi * 4 + e] + bb1[nj] * G;     // (i in A, j in B)
                if (diag) {
                    int il = wrow + mi * 16 + fq * 4 + e;
                    int jl = wcol + nj * 16 + fr;
                    if (il != jl) sum += fmaxf(tij, 0.f);
                } else {
                    float tji = t1b[nj] + ba1[mi * 4 + e] * G; // mirrored order
                    sum += fmaxf(tij, 0.f) + fmaxf(tji, 0.f);
                }
            }
        }
    }
#pragma unroll
    for (int off = 32; off; off >>= 1) sum += __shfl_xor(sum, off);
    __shared__ float redf[4];
    if (lane == 0) redf[w] = sum;
    __syncthreads();
    if (tid == 0) icp[icid] = redf[0] + redf[1] + redf[2] + redf[3];
}

// ---------------- finalize: deterministic ordered reduction ----------------
__global__ __launch_bounds__(1024) void fin_kernel(const float* __restrict__ nll,
                                                   const float* __restrict__ icp,
                                                   float* __restrict__ out) {
    int tid = threadIdx.x;
    double s = 0.0;
    for (int i = tid; i < NB; i += 1024) s += (double)nll[i];
    double s2 = (tid < NIC) ? (double)icp[tid] : 0.0;
#pragma unroll
    for (int off = 32; off; off >>= 1) {
        s  += __shfl_xor(s, off);
        s2 += __shfl_xor(s2, off);
    }
    __shared__ double sm[16], sm2[16];
    int w = tid >> 6, lane = tid & 63;
    if (lane == 0) { sm[w] = s; sm2[w] = s2; }
    __syncthreads();
    if (tid == 0) {
        double a = 0.0, c = 0.0;
        for (int i = 0; i < 16; ++i) { a += sm[i]; c += sm2[i]; }
        double cls = a / (double)NB;
        double ic  = c / ((double)NC * (double)(NC - 1));
        out[0] = (float)(cls + 0.05 * ic);
        out[1] = (float)cls;
        out[2] = (float)ic;
    }
}

extern "C" void kernel_launch(void* const* d_in, const int* in_sizes, int n_in,
                              void* d_out, int out_size, void* d_ws, size_t ws_size,
                              hipStream_t stream) {
    const float* logits  = (const float*)d_in[0];
    const int*   targets = (const int*)d_in[1];
    const float* prot    = (const float*)d_in[2];
    const float* bnd     = (const float*)d_in[3];
    float* out = (float*)d_out;
    char* ws = (char*)d_ws;
    float* nll = (float*)(ws + WS_NLL);
    float* icp = (float*)(ws + WS_ICP);
    float* t1  = (float*)(ws + WS_T1);
    unsigned short* P16 = (unsigned short*)(ws + WS_P16);
    bool pre = ws_size >= (size_t)WS_P16 + 2ull * NC * ND;

    if (pre) {
        prep_kernel<true><<<NC / 4, 256, 0, stream>>>(prot, bnd, t1, P16);
        ic_kernel<true><<<NIC, 256, 0, stream>>>(P16, prot, bnd, t1, icp);
    } else {
        prep_kernel<false><<<NC / 4, 256, 0, stream>>>(prot, bnd, t1, nullptr);
        ic_kernel<false><<<NIC, 256, 0, stream>>>(nullptr, prot, bnd, t1, icp);
    }
    ce_kernel<<<NB, 256, 0, stream>>>(logits, targets, nll);
    fin_kernel<<<1, 1024, 0, stream>>>(nll, icp, out);
}

// Round 5
// 88.097 us; speedup vs baseline: 19.0726x; 1.0361x over previous
//
#include <hip/hip_runtime.h>
#include <hip/hip_bf16.h>

// B=16384 rows of logits[B,4096]; prototypes[4096,768]; boundaries[4096]
#define NB 16384
#define NC 4096
#define ND 768
#define NT 32              // 4096/128 tiles per dim
#define NIC 528            // NT*(NT+1)/2 upper-triangle tile pairs (symmetry)
#define CE_BLOCKS 2048     // 8 rows per block, 2 rows per wave

// ws layout:
#define WS_NLLP 0          // double nllp[2048]   (per-block CE partial sums)
#define WS_ICP  16384      // float icp[528]
#define WS_T1   20480      // float t1[4096] = (1-b_i)*||p_i||^2 (fp32 exact)
#define WS_P16  36864      // ushort P16[4096*768] bf16 prototypes

// LESSON (R2/R3): fusing CE+IC into one kernel merges register pressure ->
// scratch spills + fat occupancy footprint for every block -> 11-19x loss.
// LESSON (R4): IC blocks all fit in ONE resident round (4 blocks/CU via LDS);
// IC cost is a single block's latency (~5-10us) -> total is CE-dominated.

typedef __bf16 bf16x8 __attribute__((ext_vector_type(8)));
typedef float  f32x4  __attribute__((ext_vector_type(4)));

__device__ __forceinline__ unsigned short f2bf(float f) {
    return __builtin_bit_cast(unsigned short, __float2bfloat16(f));
}

// ---------------- prep: per-row ||p||^2 (fp32) + bf16 convert ----------------
template<bool PRECONV>
__global__ __launch_bounds__(256) void prep_kernel(const float* __restrict__ prot,
                                                   const float* __restrict__ bnd,
                                                   float* __restrict__ t1,
                                                   unsigned short* __restrict__ P16) {
    int w = threadIdx.x >> 6;
    int lane = threadIdx.x & 63;
    int row = blockIdx.x * 4 + w;
    const float4* rp = reinterpret_cast<const float4*>(prot + (size_t)row * ND);
    float ss = 0.f;
#pragma unroll
    for (int it = 0; it < 3; ++it) {
        int idx = it * 64 + lane;            // 192 float4 per row
        float4 v = rp[idx];
        ss += v.x * v.x + v.y * v.y + v.z * v.z + v.w * v.w;
        if (PRECONV) {
            ushort4 h;
            h.x = f2bf(v.x); h.y = f2bf(v.y); h.z = f2bf(v.z); h.w = f2bf(v.w);
            *reinterpret_cast<ushort4*>(P16 + (size_t)row * ND + idx * 4) = h;
        }
    }
#pragma unroll
    for (int off = 32; off; off >>= 1) ss += __shfl_xor(ss, off);
    if (lane == 0) t1[row] = (1.f - bnd[row]) * ss;
}

// ---------------- cross-entropy: one ROW PER WAVE, 8 rows per block ---------
// No __syncthreads in the hot path; exact two-pass logsumexp on 16
// register-resident float4 per lane; per-block double partial out.
__global__ __launch_bounds__(256) void ce_kernel(const float* __restrict__ logits,
                                                 const int* __restrict__ targets,
                                                 double* __restrict__ nllp) {
    const int tid = threadIdx.x;
    const int w = tid >> 6, lane = tid & 63;
    const int b = blockIdx.x;
    float wave_nll = 0.f;
#pragma unroll
    for (int r = 0; r < 2; ++r) {
        const int row = b * 8 + w * 2 + r;
        const int t = targets[row];                               // broadcast
        const float4* rp = reinterpret_cast<const float4*>(logits + (size_t)row * NC);
        const float xt = logits[(size_t)row * NC + t];            // issued early
        float4 v[16];
#pragma unroll
        for (int k = 0; k < 16; ++k) v[k] = rp[lane + 64 * k];    // 1KB/instr coalesced
        float m = -3.4e38f;
#pragma unroll
        for (int k = 0; k < 16; ++k)
            m = fmaxf(m, fmaxf(fmaxf(v[k].x, v[k].y), fmaxf(v[k].z, v[k].w)));
#pragma unroll
        for (int off = 32; off; off >>= 1) m = fmaxf(m, __shfl_xor(m, off));
        float s = 0.f;
#pragma unroll
        for (int k = 0; k < 16; ++k)
            s += __expf(v[k].x - m) + __expf(v[k].y - m) + __expf(v[k].z - m) + __expf(v[k].w - m);
#pragma unroll
        for (int off = 32; off; off >>= 1) s += __shfl_xor(s, off);
        wave_nll += m + __logf(s) - xt;
    }
    __shared__ float wp[4];
    if (lane == 0) wp[w] = wave_nll;
    __syncthreads();
    if (tid == 0) nllp[b] = (double)((wp[0] + wp[1]) + (wp[2] + wp[3]));
}

// ---------------- IC: symmetric 128x128 Gram tiles (upper-tri pairs) --------
template<bool PRECONV>
__global__ __launch_bounds__(256) void ic_kernel(const unsigned short* __restrict__ P16,
                                                 const float* __restrict__ prot,
                                                 const float* __restrict__ bnd,
                                                 const float* __restrict__ t1,
                                                 float* __restrict__ icp) {
    __shared__ __bf16 As[128][72];
    __shared__ __bf16 Bs[128][72];
    const int tid = threadIdx.x;

    const int icid = blockIdx.x;
    int u = icid, bi = 0;
    while (u >= NT - bi) { u -= NT - bi; ++bi; }
    const int bj = bi + u;
    const bool diag = (bi == bj);
    const int row0 = bi * 128, col0 = bj * 128;

    const int lane = tid & 63, w = tid >> 6;
    const int fr = lane & 15, fq = lane >> 4;
    const int wrow = (w >> 1) * 64, wcol = (w & 1) * 64;

    f32x4 acc[4][4];
#pragma unroll
    for (int mi = 0; mi < 4; ++mi)
#pragma unroll
        for (int nj = 0; nj < 4; ++nj) acc[mi][nj] = (f32x4){0.f, 0.f, 0.f, 0.f};

    for (int kt = 0; kt < ND / 64; ++kt) {
        if (PRECONV) {
#pragma unroll
            for (int s2 = 0; s2 < 4; ++s2) {
                int c = tid + 256 * s2;          // 1024 chunks of 8 bf16 per tile
                int r = c >> 3, k8 = c & 7;
                uint4 va = *reinterpret_cast<const uint4*>(P16 + (size_t)(row0 + r) * ND + kt * 64 + k8 * 8);
                *reinterpret_cast<uint4*>(&As[r][k8 * 8]) = va;
                uint4 vb = *reinterpret_cast<const uint4*>(P16 + (size_t)(col0 + r) * ND + kt * 64 + k8 * 8);
                *reinterpret_cast<uint4*>(&Bs[r][k8 * 8]) = vb;
            }
        } else {
#pragma unroll
            for (int s2 = 0; s2 < 8; ++s2) {
                int c = tid + 256 * s2;          // 2048 chunks of 4 floats per tile
                int r = c >> 4, k4 = c & 15;
                float4 va = *reinterpret_cast<const float4*>(prot + (size_t)(row0 + r) * ND + kt * 64 + k4 * 4);
                ushort4 ha; ha.x = f2bf(va.x); ha.y = f2bf(va.y); ha.z = f2bf(va.z); ha.w = f2bf(va.w);
                *reinterpret_cast<ushort4*>(&As[r][k4 * 4]) = ha;
                float4 vb = *reinterpret_cast<const float4*>(prot + (size_t)(col0 + r) * ND + kt * 64 + k4 * 4);
                ushort4 hb; hb.x = f2bf(vb.x); hb.y = f2bf(vb.y); hb.z = f2bf(vb.z); hb.w = f2bf(vb.w);
                *reinterpret_cast<ushort4*>(&Bs[r][k4 * 4]) = hb;
            }
        }
        __syncthreads();
#pragma unroll
        for (int ks = 0; ks < 64; ks += 32) {
            bf16x8 af[4], bfv[4];
#pragma unroll
            for (int mi = 0; mi < 4; ++mi)
                af[mi] = *reinterpret_cast<const bf16x8*>(&As[wrow + mi * 16 + fr][ks + fq * 8]);
#pragma unroll
            for (int nj = 0; nj < 4; ++nj)
                bfv[nj] = *reinterpret_cast<const bf16x8*>(&Bs[wcol + nj * 16 + fr][ks + fq * 8]);
#pragma unroll
            for (int mi = 0; mi < 4; ++mi)
#pragma unroll
                for (int nj = 0; nj < 4; ++nj)
                    acc[mi][nj] = __builtin_amdgcn_mfma_f32_16x16x32_bf16(af[mi], bfv[nj], acc[mi][nj], 0, 0, 0);
        }
        __syncthreads();
    }

    // epilogue: tij = t1[i] + (b_j-1)*G ; off-diag pairs also add the mirror
    float t1a[16], ba1[16];
#pragma unroll
    for (int mi = 0; mi < 4; ++mi)
#pragma unroll
        for (int e = 0; e < 4; ++e) {
            int i = row0 + wrow + mi * 16 + fq * 4 + e;
            t1a[mi * 4 + e] = t1[i];
            ba1[mi * 4 + e] = bnd[i] - 1.f;
        }
    float t1b[4], bb1[4];
#pragma unroll
    for (int nj = 0; nj < 4; ++nj) {
        int j = col0 + wcol + nj * 16 + fr;
        t1b[nj] = t1[j];
        bb1[nj] = bnd[j] - 1.f;
    }

    float sum = 0.f;
#pragma unroll
    for (int mi = 0; mi < 4; ++mi) {
#pragma unroll
        for (int nj = 0; nj < 4; ++nj) {
#pragma unroll
            for (int e = 0; e < 4; ++e) {
                float G = acc[mi][nj][e];
                float tij = t1a[mi * 4 + e] + bb1[nj] * G;     // (i in A, j in B)
                if (diag) {
                    int il = wrow + mi * 16 + fq * 4 + e;
                    int jl = wcol + nj * 16 + fr;
                    if (il != jl) sum += fmaxf(tij, 0.f);
                } else {
                    float tji = t1b[nj] + ba1[mi * 4 + e] * G; // mirrored order
                    sum += fmaxf(tij, 0.f) + fmaxf(tji, 0.f);
                }
            }
        }
    }
#pragma unroll
    for (int off = 32; off; off >>= 1) sum += __shfl_xor(sum, off);
    __shared__ float redf[4];
    if (lane == 0) redf[w] = sum;
    __syncthreads();
    if (tid == 0) icp[icid] = redf[0] + redf[1] + redf[2] + redf[3];
}

// ---------------- finalize: deterministic ordered reduction ----------------
__global__ __launch_bounds__(1024) void fin_kernel(const double* __restrict__ nllp,
                                                   const float* __restrict__ icp,
                                                   float* __restrict__ out) {
    int tid = threadIdx.x;
    double s = nllp[tid] + nllp[tid + 1024];       // 2048 partials
    double s2 = (tid < NIC) ? (double)icp[tid] : 0.0;
#pragma unroll
    for (int off = 32; off; off >>= 1) {
        s  += __shfl_xor(s, off);
        s2 += __shfl_xor(s2, off);
    }
    __shared__ double sm[16], sm2[16];
    int w = tid >> 6, lane = tid & 63;
    if (lane == 0) { sm[w] = s; sm2[w] = s2; }
    __syncthreads();
    if (tid == 0) {
        double a = 0.0, c = 0.0;
        for (int i = 0; i < 16; ++i) { a += sm[i]; c += sm2[i]; }
        double cls = a / (double)NB;
        double ic  = c / ((double)NC * (double)(NC - 1));
        out[0] = (float)(cls + 0.05 * ic);
        out[1] = (float)cls;
        out[2] = (float)ic;
    }
}

extern "C" void kernel_launch(void* const* d_in, const int* in_sizes, int n_in,
                              void* d_out, int out_size, void* d_ws, size_t ws_size,
                              hipStream_t stream) {
    const float* logits  = (const float*)d_in[0];
    const int*   targets = (const int*)d_in[1];
    const float* prot    = (const float*)d_in[2];
    const float* bnd     = (const float*)d_in[3];
    float* out = (float*)d_out;
    char* ws = (char*)d_ws;
    double* nllp = (double*)(ws + WS_NLLP);
    float* icp = (float*)(ws + WS_ICP);
    float* t1  = (float*)(ws + WS_T1);
    unsigned short* P16 = (unsigned short*)(ws + WS_P16);
    bool pre = ws_size >= (size_t)WS_P16 + 2ull * NC * ND;

    if (pre) {
        prep_kernel<true><<<NC / 4, 256, 0, stream>>>(prot, bnd, t1, P16);
        ic_kernel<true><<<NIC, 256, 0, stream>>>(P16, prot, bnd, t1, icp);
    } else {
        prep_kernel<false><<<NC / 4, 256, 0, stream>>>(prot, bnd, t1, nullptr);
        ic_kernel<false><<<NIC, 256, 0, stream>>>(nullptr, prot, bnd, t1, icp);
    }
    ce_kernel<<<CE_BLOCKS, 256, 0, stream>>>(logits, targets, nllp);
    fin_kernel<<<1, 1024, 0, stream>>>(nllp, icp, out);
}